// Round 1
// baseline (247.254 us; speedup 1.0000x reference)
//
#include <hip/hip_runtime.h>
#include <hip/hip_bf16.h>

typedef __attribute__((ext_vector_type(8))) short short8;
typedef __attribute__((ext_vector_type(4))) float f32x4;

#define D   512
#define NQ  2048
#define NS  4096
#define NB  8
#define BM  128
#define BN  128
#define BK  32

// round-to-nearest-even fp32 -> bf16 bits
__device__ __forceinline__ short f2bf(float f) {
  unsigned u = __builtin_bit_cast(unsigned, f);
  unsigned r = u + 0x7fffu + ((u >> 16) & 1u);
  return (short)(r >> 16);
}

__device__ __forceinline__ short8 pack8(float4 a, float4 b, float r) {
  short8 o;
  o[0] = f2bf(a.x * r); o[1] = f2bf(a.y * r); o[2] = f2bf(a.z * r); o[3] = f2bf(a.w * r);
  o[4] = f2bf(b.x * r); o[5] = f2bf(b.y * r); o[6] = f2bf(b.z * r); o[7] = f2bf(b.w * r);
  return o;
}

// One wave per row: reciprocal L2 norm (matches torch F.normalize: x / max(||x||, eps))
__global__ void norms_kernel(const float* __restrict__ q, const float* __restrict__ s,
                             float* __restrict__ rq, float* __restrict__ rs) {
  int wave = blockIdx.x * 4 + (threadIdx.x >> 6);
  int lane = threadIdx.x & 63;
  const int NQR = NB * NQ, NSR = NB * NS;
  if (wave >= NQR + NSR) return;
  const float4* r4;
  float* outp;
  if (wave < NQR) { r4 = (const float4*)(q + (size_t)wave * D); outp = rq + wave; }
  else           { r4 = (const float4*)(s + (size_t)(wave - NQR) * D); outp = rs + (wave - NQR); }
  float4 a = r4[lane];
  float4 b = r4[lane + 64];
  float ss = a.x*a.x + a.y*a.y + a.z*a.z + a.w*a.w
           + b.x*b.x + b.y*b.y + b.z*b.z + b.w*b.w;
  #pragma unroll
  for (int m = 32; m >= 1; m >>= 1) ss += __shfl_xor(ss, m, 64);
  if (lane == 0) *outp = 1.0f / fmaxf(sqrtf(ss), 1e-12f);
}

// 128x128 tile: cos = Qn * Sn^T via bf16 MFMA, fused normalize+convert in staging,
// per-q-row max over the tile's 128 support cols, publish via encoded atomicMax.
__global__ __launch_bounds__(256, 3) void cosmax_kernel(
    const float* __restrict__ Q, const float* __restrict__ S,
    const float* __restrict__ rq, const float* __restrict__ rs,
    unsigned int* __restrict__ maxenc)
{
  __shared__ short As[BM * BK];        // row-major, stride BK (bf16 bits)
  __shared__ short Bs[BN * BK];
  __shared__ float maxbuf[BM][2];

  const int b  = blockIdx.z;
  const int mt = blockIdx.y;   // 0..15
  const int nt = blockIdx.x;   // 0..31

  const float* Qb  = Q + ((size_t)b * NQ + mt * BM) * D;
  const float* Sb  = S + ((size_t)b * NS + nt * BN) * D;
  const float* rqb = rq + (size_t)b * NQ + mt * BM;
  const float* rsb = rs + (size_t)b * NS + nt * BN;

  const int tid  = threadIdx.x;
  const int srow = tid >> 2;         // 0..63 (also +64)
  const int kseg = (tid & 3) * 8;    // 0,8,16,24

  const float rq0 = rqb[srow], rq1 = rqb[srow + 64];
  const float rs0 = rsb[srow], rs1 = rsb[srow + 64];

  const int wave = tid >> 6;         // 0..3
  const int lane = tid & 63;
  const int wm = (wave & 1) * 64;
  const int wn = (wave >> 1) * 64;
  const int lm = lane & 15;
  const int lk = (lane >> 4) * 8;

  f32x4 acc[4][4];
  #pragma unroll
  for (int i = 0; i < 4; ++i)
    #pragma unroll
    for (int j = 0; j < 4; ++j)
      acc[i][j] = (f32x4){0.f, 0.f, 0.f, 0.f};

  const float* qrow0 = Qb + (size_t)srow * D + kseg;
  const float* qrow1 = qrow0 + (size_t)64 * D;
  const float* srow0 = Sb + (size_t)srow * D + kseg;
  const float* srow1 = srow0 + (size_t)64 * D;

  float4 qa, qb2, qc, qd, sa, sb2, sc, sd;
  #define LOADK(k0)                                                    \
    qa  = *(const float4*)(qrow0 + (k0));  qb2 = *(const float4*)(qrow0 + (k0) + 4); \
    qc  = *(const float4*)(qrow1 + (k0));  qd  = *(const float4*)(qrow1 + (k0) + 4); \
    sa  = *(const float4*)(srow0 + (k0));  sb2 = *(const float4*)(srow0 + (k0) + 4); \
    sc  = *(const float4*)(srow1 + (k0));  sd  = *(const float4*)(srow1 + (k0) + 4);

  LOADK(0);

  #pragma unroll 4
  for (int kt = 0; kt < D / BK; ++kt) {
    // stage current chunk: normalize + cvt bf16 + 16B LDS writes
    *(short8*)&As[srow        * BK + kseg] = pack8(qa, qb2, rq0);
    *(short8*)&As[(srow + 64) * BK + kseg] = pack8(qc, qd,  rq1);
    *(short8*)&Bs[srow        * BK + kseg] = pack8(sa, sb2, rs0);
    *(short8*)&Bs[(srow + 64) * BK + kseg] = pack8(sc, sd,  rs1);
    __syncthreads();

    if (kt < D / BK - 1) { LOADK((kt + 1) * BK); }   // prefetch overlaps MFMA

    short8 af[4], bf[4];
    #pragma unroll
    for (int i = 0; i < 4; ++i) af[i] = *(short8*)&As[(wm + i * 16 + lm) * BK + lk];
    #pragma unroll
    for (int j = 0; j < 4; ++j) bf[j] = *(short8*)&Bs[(wn + j * 16 + lm) * BK + lk];

    #pragma unroll
    for (int i = 0; i < 4; ++i)
      #pragma unroll
      for (int j = 0; j < 4; ++j)
        acc[i][j] = __builtin_amdgcn_mfma_f32_16x16x32_bf16(af[i], bf[j], acc[i][j], 0, 0, 0);

    __syncthreads();
  }
  #undef LOADK

  // epilogue: per-lane max over j (4 cols each), then across the 16 lanes sharing m
  #pragma unroll
  for (int i = 0; i < 4; ++i) {
    #pragma unroll
    for (int r = 0; r < 4; ++r) {
      float v = fmaxf(fmaxf(acc[i][0][r], acc[i][1][r]),
                      fmaxf(acc[i][2][r], acc[i][3][r]));
      v = fmaxf(v, __shfl_xor(v, 1, 64));
      v = fmaxf(v, __shfl_xor(v, 2, 64));
      v = fmaxf(v, __shfl_xor(v, 4, 64));
      v = fmaxf(v, __shfl_xor(v, 8, 64));
      if ((lane & 15) == 0) {
        int row = wm + i * 16 + (lane >> 4) * 4 + r;   // C/D: row=(lane>>4)*4+reg
        maxbuf[row][wave >> 1] = v;                    // waves {0,1} col0, {2,3} col1
      }
    }
  }
  __syncthreads();

  if (tid < BM) {
    float v = fmaxf(maxbuf[tid][0], maxbuf[tid][1]);
    unsigned e = __builtin_bit_cast(unsigned, v);
    e = ((int)e >= 0) ? (e | 0x80000000u) : ~e;        // monotone float->uint
    atomicMax(&maxenc[(size_t)b * NQ + mt * BM + tid], e);
  }
}

__global__ void finalize_kernel(const unsigned* __restrict__ maxenc,
                                float* __restrict__ out) {
  int b = blockIdx.x;
  int tid = threadIdx.x;
  float sum = 0.f;
  for (int i = tid; i < NQ; i += 256) {
    unsigned e = maxenc[(size_t)b * NQ + i];
    unsigned u = (e & 0x80000000u) ? (e & 0x7fffffffu) : ~e;
    float v = __builtin_bit_cast(float, u);
    sum += 1.0f - v;
  }
  #pragma unroll
  for (int m = 32; m >= 1; m >>= 1) sum += __shfl_xor(sum, m, 64);
  __shared__ float part[4];
  if ((tid & 63) == 0) part[tid >> 6] = sum;
  __syncthreads();
  if (tid == 0) out[b] = (part[0] + part[1] + part[2] + part[3]) * (1.0f / (float)NQ);
}

extern "C" void kernel_launch(void* const* d_in, const int* in_sizes, int n_in,
                              void* d_out, int out_size, void* d_ws, size_t ws_size,
                              hipStream_t stream) {
  const float* q = (const float*)d_in[0];   // [8,2048,512]
  const float* s = (const float*)d_in[1];   // [8,4096,512]
  float* out = (float*)d_out;               // [8]

  unsigned* maxenc = (unsigned*)d_ws;                         // 64 KB
  float* rq = (float*)((char*)d_ws + 65536);                  // 64 KB
  float* rs = (float*)((char*)d_ws + 131072);                 // 128 KB

  hipMemsetAsync(maxenc, 0, (size_t)NB * NQ * sizeof(unsigned), stream);

  int nrows = NB * (NQ + NS);               // 49152 rows, 4 waves/block
  norms_kernel<<<nrows / 4, 256, 0, stream>>>(q, s, rq, rs);

  dim3 grid(NS / BN, NQ / BM, NB);          // 32 x 16 x 8 = 4096 blocks
  cosmax_kernel<<<grid, 256, 0, stream>>>(q, s, rq, rs, maxenc);

  finalize_kernel<<<NB, 256, 0, stream>>>(maxenc, out);
}

// Round 2
// 206.641 us; speedup vs baseline: 1.1965x; 1.1965x over previous
//
#include <hip/hip_runtime.h>
#include <hip/hip_bf16.h>

typedef __attribute__((ext_vector_type(8))) short short8;
typedef __attribute__((ext_vector_type(4))) float f32x4;

#define D   512
#define NQ  2048
#define NS  4096
#define NB  8
#define BM  128
#define BN  128
#define BK  32

typedef const __attribute__((address_space(1))) unsigned int gas_uint;
typedef __attribute__((address_space(3))) unsigned int las_uint;

// round-to-nearest-even fp32 -> bf16 bits
__device__ __forceinline__ short f2bf(float f) {
  unsigned u = __builtin_bit_cast(unsigned, f);
  unsigned r = u + 0x7fffu + ((u >> 16) & 1u);
  return (short)(r >> 16);
}

__device__ __forceinline__ short8 pack8(float4 a, float4 b, float r) {
  short8 o;
  o[0] = f2bf(a.x * r); o[1] = f2bf(a.y * r); o[2] = f2bf(a.z * r); o[3] = f2bf(a.w * r);
  o[4] = f2bf(b.x * r); o[5] = f2bf(b.y * r); o[6] = f2bf(b.z * r); o[7] = f2bf(b.w * r);
  return o;
}

// ============================ FAST PATH ====================================
// Fused L2-norm + normalize + fp32->bf16 convert, one wave per row.
// Blocks 0..63 also zero the maxenc accumulator (replaces the memset launch).
__global__ void normcvt_kernel(const float* __restrict__ q, const float* __restrict__ s,
                               short* __restrict__ qn, short* __restrict__ sn,
                               unsigned* __restrict__ maxenc) {
  if (blockIdx.x < 64) maxenc[(blockIdx.x << 8) | threadIdx.x] = 0;
  int wave = blockIdx.x * 4 + (threadIdx.x >> 6);
  int lane = threadIdx.x & 63;
  const int NQR = NB * NQ;
  const float4* src; short* dst;
  if (wave < NQR) { src = (const float4*)(q + (size_t)wave * D); dst = qn + (size_t)wave * D; }
  else {
    size_t w = wave - NQR;
    src = (const float4*)(s + w * D); dst = sn + w * D;
  }
  float4 a = src[lane * 2];
  float4 b = src[lane * 2 + 1];
  float ss = a.x*a.x + a.y*a.y + a.z*a.z + a.w*a.w
           + b.x*b.x + b.y*b.y + b.z*b.z + b.w*b.w;
  #pragma unroll
  for (int m = 32; m >= 1; m >>= 1) ss += __shfl_xor(ss, m, 64);
  float r = 1.0f / fmaxf(sqrtf(ss), 1e-12f);
  *(short8*)(dst + lane * 8) = pack8(a, b, r);
}

// m97-structure GEMM tile: bf16 inputs, global_load_lds width-16 staging,
// per-q-row max over 128 support cols, encoded atomicMax publish.
__global__ __launch_bounds__(256, 3) void cosmax2_kernel(
    const short* __restrict__ Qn, const short* __restrict__ Sn,
    unsigned int* __restrict__ maxenc)
{
  __shared__ short As[BM * BK];        // row-major [128][32] bf16 bits
  __shared__ short Bs[BN * BK];
  __shared__ float maxbuf[BM][2];

  const int b  = blockIdx.z;
  const int mt = blockIdx.y;
  const int nt = blockIdx.x;
  const int tid  = threadIdx.x;
  const int wave = tid >> 6;
  const int lane = tid & 63;

  // ---- staging maps: instr t in {0,1}; lane covers (row = wave*32 + t*16 + lane/4,
  //      kchunk = lane%4); LDS dest = contiguous row-major, base wave-uniform.
  const int r0 = wave * 32 + (lane >> 2);
  const int kc = lane & 3;
  const short* ga0 = Qn + ((size_t)b * NQ + mt * BM + r0) * D + kc * 8;
  const short* ga1 = ga0 + (size_t)16 * D;
  const short* gb0 = Sn + ((size_t)b * NS + nt * BN + r0) * D + kc * 8;
  const short* gb1 = gb0 + (size_t)16 * D;
  short* la0 = As + wave * 1024;   // bytes: wave*2048
  short* la1 = la0 + 512;
  short* lb0 = Bs + wave * 1024;
  short* lb1 = lb0 + 512;

  const int wm = (wave & 1) * 64;
  const int wn = (wave >> 1) * 64;
  const int lm = lane & 15;
  const int lk = (lane >> 4) * 8;

  f32x4 acc[4][4];
  #pragma unroll
  for (int i = 0; i < 4; ++i)
    #pragma unroll
    for (int j = 0; j < 4; ++j)
      acc[i][j] = (f32x4){0.f, 0.f, 0.f, 0.f};

  for (int kt = 0; kt < D / BK; ++kt) {
    const int ko = kt * BK;  // shorts
    __builtin_amdgcn_global_load_lds((gas_uint*)(ga0 + ko), (las_uint*)la0, 16, 0, 0);
    __builtin_amdgcn_global_load_lds((gas_uint*)(ga1 + ko), (las_uint*)la1, 16, 0, 0);
    __builtin_amdgcn_global_load_lds((gas_uint*)(gb0 + ko), (las_uint*)lb0, 16, 0, 0);
    __builtin_amdgcn_global_load_lds((gas_uint*)(gb1 + ko), (las_uint*)lb1, 16, 0, 0);
    __syncthreads();

    short8 af[4], bf[4];
    #pragma unroll
    for (int i = 0; i < 4; ++i) af[i] = *(const short8*)&As[(wm + i * 16 + lm) * BK + lk];
    #pragma unroll
    for (int j = 0; j < 4; ++j) bf[j] = *(const short8*)&Bs[(wn + j * 16 + lm) * BK + lk];

    #pragma unroll
    for (int i = 0; i < 4; ++i)
      #pragma unroll
      for (int j = 0; j < 4; ++j)
        acc[i][j] = __builtin_amdgcn_mfma_f32_16x16x32_bf16(af[i], bf[j], acc[i][j], 0, 0, 0);

    __syncthreads();
  }

  // epilogue: per-row max over this tile's 128 cols, then encoded atomicMax
  #pragma unroll
  for (int i = 0; i < 4; ++i) {
    #pragma unroll
    for (int r = 0; r < 4; ++r) {
      float v = fmaxf(fmaxf(acc[i][0][r], acc[i][1][r]),
                      fmaxf(acc[i][2][r], acc[i][3][r]));
      v = fmaxf(v, __shfl_xor(v, 1, 64));
      v = fmaxf(v, __shfl_xor(v, 2, 64));
      v = fmaxf(v, __shfl_xor(v, 4, 64));
      v = fmaxf(v, __shfl_xor(v, 8, 64));
      if ((lane & 15) == 0) {
        int row = wm + i * 16 + (lane >> 4) * 4 + r;   // C/D: row=(lane>>4)*4+reg
        maxbuf[row][wave >> 1] = v;
      }
    }
  }
  __syncthreads();

  if (tid < BM) {
    float v = fmaxf(maxbuf[tid][0], maxbuf[tid][1]);
    unsigned e = __builtin_bit_cast(unsigned, v);
    e = ((int)e >= 0) ? (e | 0x80000000u) : ~e;        // monotone float->uint
    atomicMax(&maxenc[(size_t)b * NQ + mt * BM + tid], e);
  }
}

__global__ void finalize_kernel(const unsigned* __restrict__ maxenc,
                                float* __restrict__ out) {
  int b = blockIdx.x;
  int tid = threadIdx.x;
  float sum = 0.f;
  for (int i = tid; i < NQ; i += 256) {
    unsigned e = maxenc[(size_t)b * NQ + i];
    unsigned u = (e & 0x80000000u) ? (e & 0x7fffffffu) : ~e;
    float v = __builtin_bit_cast(float, u);
    sum += 1.0f - v;
  }
  #pragma unroll
  for (int m = 32; m >= 1; m >>= 1) sum += __shfl_xor(sum, m, 64);
  __shared__ float part[4];
  if ((tid & 63) == 0) part[tid >> 6] = sum;
  __syncthreads();
  if (tid == 0) out[b] = (part[0] + part[1] + part[2] + part[3]) * (1.0f / (float)NQ);
}

// ====================== FALLBACK PATH (round-1, proven) =====================
__global__ void norms_kernel(const float* __restrict__ q, const float* __restrict__ s,
                             float* __restrict__ rq, float* __restrict__ rs) {
  int wave = blockIdx.x * 4 + (threadIdx.x >> 6);
  int lane = threadIdx.x & 63;
  const int NQR = NB * NQ, NSR = NB * NS;
  if (wave >= NQR + NSR) return;
  const float4* r4; float* outp;
  if (wave < NQR) { r4 = (const float4*)(q + (size_t)wave * D); outp = rq + wave; }
  else           { r4 = (const float4*)(s + (size_t)(wave - NQR) * D); outp = rs + (wave - NQR); }
  float4 a = r4[lane];
  float4 b = r4[lane + 64];
  float ss = a.x*a.x + a.y*a.y + a.z*a.z + a.w*a.w
           + b.x*b.x + b.y*b.y + b.z*b.z + b.w*b.w;
  #pragma unroll
  for (int m = 32; m >= 1; m >>= 1) ss += __shfl_xor(ss, m, 64);
  if (lane == 0) *outp = 1.0f / fmaxf(sqrtf(ss), 1e-12f);
}

__global__ __launch_bounds__(256, 3) void cosmax_kernel(
    const float* __restrict__ Q, const float* __restrict__ S,
    const float* __restrict__ rq, const float* __restrict__ rs,
    unsigned int* __restrict__ maxenc)
{
  __shared__ short As[BM * BK];
  __shared__ short Bs[BN * BK];
  __shared__ float maxbuf[BM][2];

  const int b  = blockIdx.z, mt = blockIdx.y, nt = blockIdx.x;
  const float* Qb  = Q + ((size_t)b * NQ + mt * BM) * D;
  const float* Sb  = S + ((size_t)b * NS + nt * BN) * D;
  const float* rqb = rq + (size_t)b * NQ + mt * BM;
  const float* rsb = rs + (size_t)b * NS + nt * BN;

  const int tid  = threadIdx.x;
  const int srow = tid >> 2;
  const int kseg = (tid & 3) * 8;
  const float rq0 = rqb[srow], rq1 = rqb[srow + 64];
  const float rs0 = rsb[srow], rs1 = rsb[srow + 64];
  const int wave = tid >> 6, lane = tid & 63;
  const int wm = (wave & 1) * 64, wn = (wave >> 1) * 64;
  const int lm = lane & 15, lk = (lane >> 4) * 8;

  f32x4 acc[4][4];
  #pragma unroll
  for (int i = 0; i < 4; ++i)
    #pragma unroll
    for (int j = 0; j < 4; ++j) acc[i][j] = (f32x4){0.f, 0.f, 0.f, 0.f};

  const float* qrow0 = Qb + (size_t)srow * D + kseg;
  const float* qrow1 = qrow0 + (size_t)64 * D;
  const float* srow0 = Sb + (size_t)srow * D + kseg;
  const float* srow1 = srow0 + (size_t)64 * D;

  float4 qa, qb2, qc, qd, sa, sb2, sc, sd;
  #define LOADK(k0)                                                    \
    qa  = *(const float4*)(qrow0 + (k0));  qb2 = *(const float4*)(qrow0 + (k0) + 4); \
    qc  = *(const float4*)(qrow1 + (k0));  qd  = *(const float4*)(qrow1 + (k0) + 4); \
    sa  = *(const float4*)(srow0 + (k0));  sb2 = *(const float4*)(srow0 + (k0) + 4); \
    sc  = *(const float4*)(srow1 + (k0));  sd  = *(const float4*)(srow1 + (k0) + 4);
  LOADK(0);
  #pragma unroll 4
  for (int kt = 0; kt < D / BK; ++kt) {
    *(short8*)&As[srow        * BK + kseg] = pack8(qa, qb2, rq0);
    *(short8*)&As[(srow + 64) * BK + kseg] = pack8(qc, qd,  rq1);
    *(short8*)&Bs[srow        * BK + kseg] = pack8(sa, sb2, rs0);
    *(short8*)&Bs[(srow + 64) * BK + kseg] = pack8(sc, sd,  rs1);
    __syncthreads();
    if (kt < D / BK - 1) { LOADK((kt + 1) * BK); }
    short8 af[4], bf[4];
    #pragma unroll
    for (int i = 0; i < 4; ++i) af[i] = *(short8*)&As[(wm + i * 16 + lm) * BK + lk];
    #pragma unroll
    for (int j = 0; j < 4; ++j) bf[j] = *(short8*)&Bs[(wn + j * 16 + lm) * BK + lk];
    #pragma unroll
    for (int i = 0; i < 4; ++i)
      #pragma unroll
      for (int j = 0; j < 4; ++j)
        acc[i][j] = __builtin_amdgcn_mfma_f32_16x16x32_bf16(af[i], bf[j], acc[i][j], 0, 0, 0);
    __syncthreads();
  }
  #undef LOADK

  #pragma unroll
  for (int i = 0; i < 4; ++i) {
    #pragma unroll
    for (int r = 0; r < 4; ++r) {
      float v = fmaxf(fmaxf(acc[i][0][r], acc[i][1][r]),
                      fmaxf(acc[i][2][r], acc[i][3][r]));
      v = fmaxf(v, __shfl_xor(v, 1, 64));
      v = fmaxf(v, __shfl_xor(v, 2, 64));
      v = fmaxf(v, __shfl_xor(v, 4, 64));
      v = fmaxf(v, __shfl_xor(v, 8, 64));
      if ((lane & 15) == 0) {
        int row = wm + i * 16 + (lane >> 4) * 4 + r;
        maxbuf[row][wave >> 1] = v;
      }
    }
  }
  __syncthreads();
  if (tid < BM) {
    float v = fmaxf(maxbuf[tid][0], maxbuf[tid][1]);
    unsigned e = __builtin_bit_cast(unsigned, v);
    e = ((int)e >= 0) ? (e | 0x80000000u) : ~e;
    atomicMax(&maxenc[(size_t)b * NQ + mt * BM + tid], e);
  }
}

// ============================================================================
extern "C" void kernel_launch(void* const* d_in, const int* in_sizes, int n_in,
                              void* d_out, int out_size, void* d_ws, size_t ws_size,
                              hipStream_t stream) {
  const float* q = (const float*)d_in[0];   // [8,2048,512]
  const float* s = (const float*)d_in[1];   // [8,4096,512]
  float* out = (float*)d_out;               // [8]

  unsigned* maxenc = (unsigned*)d_ws;                         // 64 KB
  const size_t QOFF = 65536;
  const size_t SOFF = QOFF + (size_t)NB * NQ * D * 2;         // +16 MiB
  const size_t NEED = SOFF + (size_t)NB * NS * D * 2;         // +32 MiB  (~48.1 MiB total)

  dim3 grid(NS / BN, NQ / BM, NB);          // 32 x 16 x 8 = 4096 blocks

  if (ws_size >= NEED) {
    short* qn = (short*)((char*)d_ws + QOFF);
    short* sn = (short*)((char*)d_ws + SOFF);
    normcvt_kernel<<<NB * (NQ + NS) / 4, 256, 0, stream>>>(q, s, qn, sn, maxenc);
    cosmax2_kernel<<<grid, 256, 0, stream>>>(qn, sn, maxenc);
    finalize_kernel<<<NB, 256, 0, stream>>>(maxenc, out);
  } else {
    float* rq = (float*)((char*)d_ws + 65536);
    float* rs = (float*)((char*)d_ws + 131072);
    hipMemsetAsync(maxenc, 0, (size_t)NB * NQ * sizeof(unsigned), stream);
    norms_kernel<<<NB * (NQ + NS) / 4, 256, 0, stream>>>(q, s, rq, rs);
    cosmax_kernel<<<grid, 256, 0, stream>>>(q, s, rq, rs, maxenc);
    finalize_kernel<<<NB, 256, 0, stream>>>(maxenc, out);
  }
}